// Round 1
// baseline (735.697 us; speedup 1.0000x reference)
//
#include <hip/hip_runtime.h>
#include <math.h>

#define H   1024
#define H2  2048
#define H3  3072
#define V   50257
#define S   2048

// ws layout (float offsets)
#define WS_X   0        // x = [embedded ; last_context]   (2048)
#define WS_GI  2048     // gi (3072)
#define WS_GH  5120     // gh (3072)
#define WS_U   8192     // u = attn_W^T r (1024)
#define WS_Y   9216     // y = [rnn_output ; context] (2048)
#define WS_E   11264    // energies (2048)
#define WS_W   13312    // attn weights (2048)

__device__ __forceinline__ float wave_reduce_sum(float v) {
    #pragma unroll
    for (int off = 32; off > 0; off >>= 1) v += __shfl_down(v, off);
    return v;
}

__device__ __forceinline__ float wave_reduce_max(float v) {
    #pragma unroll
    for (int off = 32; off > 0; off >>= 1) v = fmaxf(v, __shfl_down(v, off));
    return v;
}

// K0: build x = [emb[id]; last_context]; zero accumulators (ws is 0xAA-poisoned)
__global__ void k0_prep(const int* __restrict__ ids,
                        const float* __restrict__ last_context,
                        const float* __restrict__ emb,
                        float* __restrict__ ws) {
    int i = blockIdx.x * blockDim.x + threadIdx.x;
    if (i < H2) {
        int id = ids[0];
        ws[WS_X + i] = (i < H) ? emb[(size_t)id * H + i] : last_context[i - H];
    }
    if (i < H) { ws[WS_U + i] = 0.f; ws[WS_Y + H + i] = 0.f; }
}

// K1: gi[j] = Wih[j]·x + bih[j]; gh[j] = Whh[j]·h + bhh[j].  1 wave per row j.
__global__ __launch_bounds__(256) void k1_gru_mv(const float* __restrict__ Wih,
                                                 const float* __restrict__ Whh,
                                                 const float* __restrict__ bih,
                                                 const float* __restrict__ bhh,
                                                 const float* __restrict__ hprev,
                                                 float* __restrict__ ws) {
    int wv = threadIdx.x >> 6, lane = threadIdx.x & 63;
    int j = blockIdx.x * 4 + wv;               // 768 blocks * 4 = 3072 rows exact
    const float4* wa = (const float4*)(Wih + (size_t)j * H2);
    const float4* x4 = (const float4*)(ws + WS_X);
    float a = 0.f;
    #pragma unroll
    for (int q = 0; q < 8; ++q) {
        float4 w = wa[lane + 64 * q], x = x4[lane + 64 * q];
        a += w.x * x.x + w.y * x.y + w.z * x.z + w.w * x.w;
    }
    const float4* wb = (const float4*)(Whh + (size_t)j * H);
    const float4* h4 = (const float4*)hprev;
    float b = 0.f;
    #pragma unroll
    for (int q = 0; q < 4; ++q) {
        float4 w = wb[lane + 64 * q], h = h4[lane + 64 * q];
        b += w.x * h.x + w.y * h.y + w.z * h.z + w.w * h.w;
    }
    a = wave_reduce_sum(a);
    b = wave_reduce_sum(b);
    if (lane == 0) {
        ws[WS_GI + j] = a + bih[j];
        ws[WS_GH + j] = b + bhh[j];
    }
}

// K2: GRU gates -> rnn_output; write hidden output and y[0:H]
__global__ void k2_gates(const float* __restrict__ hprev,
                         float* __restrict__ ws,
                         float* __restrict__ out) {
    int t = blockIdx.x * blockDim.x + threadIdx.x;
    if (t >= H) return;
    float gi_r = ws[WS_GI + t],        gh_r = ws[WS_GH + t];
    float gi_z = ws[WS_GI + H + t],    gh_z = ws[WS_GH + H + t];
    float gi_n = ws[WS_GI + 2*H + t],  gh_n = ws[WS_GH + 2*H + t];
    float r = 1.f / (1.f + expf(-(gi_r + gh_r)));
    float z = 1.f / (1.f + expf(-(gi_z + gh_z)));
    float n = tanhf(gi_n + r * gh_n);
    float o = (1.f - z) * n + z * hprev[t];
    ws[WS_Y + t] = o;        // first half of [rnn_output; context]
    out[V + H + t] = o;      // hidden output
}

// K3: u_k = sum_j attn_W[j][k] * r_j   (u = attn_W^T r), split-j with atomics
__global__ void k3_u(const float* __restrict__ attn_W, float* __restrict__ ws) {
    int bk = blockIdx.x & 3, bj = blockIdx.x >> 2;   // 4 k-chunks x 16 j-chunks
    int k = bk * 256 + threadIdx.x;
    int j0 = bj * 64;
    float acc = 0.f;
    for (int j = j0; j < j0 + 64; ++j)
        acc += attn_W[(size_t)j * H + k] * ws[WS_Y + j];
    atomicAdd(&ws[WS_U + k], acc);
}

// K4: energies[s] = E[s]·u.  1 wave per row s. (b·r constant dropped: softmax-invariant)
__global__ __launch_bounds__(256) void k4_energy(const float* __restrict__ enc,
                                                 float* __restrict__ ws) {
    int wv = threadIdx.x >> 6, lane = threadIdx.x & 63;
    int s = blockIdx.x * 4 + wv;               // 512 blocks * 4 = 2048 exact
    const float4* e4 = (const float4*)(enc + (size_t)s * H);
    const float4* u4 = (const float4*)(ws + WS_U);
    float a = 0.f;
    #pragma unroll
    for (int q = 0; q < 4; ++q) {
        float4 e = e4[lane + 64 * q], u = u4[lane + 64 * q];
        a += e.x * u.x + e.y * u.y + e.z * u.z + e.w * u.w;
    }
    a = wave_reduce_sum(a);
    if (lane == 0) ws[WS_E + s] = a;
}

// K5: softmax over S=2048, single block of 1024 (2 elems/thread)
__global__ __launch_bounds__(1024) void k5_softmax(float* __restrict__ ws,
                                                   float* __restrict__ out) {
    __shared__ float red[16];
    int t = threadIdx.x, wv = t >> 6, lane = t & 63;
    float e0 = ws[WS_E + t], e1 = ws[WS_E + 1024 + t];
    float m = fmaxf(e0, e1);
    m = wave_reduce_max(m);
    if (lane == 0) red[wv] = m;
    __syncthreads();
    if (t == 0) { float mm = red[0]; for (int i = 1; i < 16; ++i) mm = fmaxf(mm, red[i]); red[0] = mm; }
    __syncthreads();
    m = red[0];
    float p0 = expf(e0 - m), p1 = expf(e1 - m);
    float ssum = wave_reduce_sum(p0 + p1);
    __syncthreads();                      // red[0] read complete before reuse
    if (lane == 0) red[wv] = ssum;
    __syncthreads();
    if (t == 0) { float s2 = 0.f; for (int i = 0; i < 16; ++i) s2 += red[i]; red[0] = s2; }
    __syncthreads();
    float inv = 1.f / red[0];
    float w0 = p0 * inv, w1 = p1 * inv;
    ws[WS_W + t] = w0;            ws[WS_W + 1024 + t] = w1;
    out[V + 2*H + t] = w0;        out[V + 2*H + 1024 + t] = w1;
}

// K6: context_k = sum_s w_s * E[s][k], split-s with atomics into y[H:2H]
__global__ void k6_ctx(const float* __restrict__ enc, float* __restrict__ ws) {
    int bk = blockIdx.x & 3, bs = blockIdx.x >> 2;   // 4 k-chunks x 16 s-chunks
    int k = bk * 256 + threadIdx.x;
    int s0 = bs * 128;
    float acc = 0.f;
    for (int s = s0; s < s0 + 128; ++s)
        acc += ws[WS_W + s] * enc[(size_t)s * H + k];
    atomicAdd(&ws[WS_Y + H + k], acc);
}

// K7: logits_v = out_W[v]·[r;ctx] + out_b[v], staged into d_out[0:V]. 1 wave/row.
__global__ __launch_bounds__(256) void k7_logits(const float* __restrict__ outW,
                                                 const float* __restrict__ outb,
                                                 const float* __restrict__ ws,
                                                 float* __restrict__ out) {
    int wv = threadIdx.x >> 6, lane = threadIdx.x & 63;
    int v = blockIdx.x * 4 + wv;
    if (v >= V) return;
    const float4* w4 = (const float4*)(outW + (size_t)v * H2);
    const float4* y4 = (const float4*)(ws + WS_Y);
    float a = 0.f;
    #pragma unroll
    for (int q = 0; q < 8; ++q) {
        float4 w = w4[lane + 64 * q], y = y4[lane + 64 * q];
        a += w.x * y.x + w.y * y.y + w.z * y.z + w.w * y.w;
    }
    a = wave_reduce_sum(a);
    if (lane == 0) out[v] = a + outb[v];
}

// K8: log_softmax over V in place; also write context output. Single block of 1024.
__global__ __launch_bounds__(1024) void k8_finalize(const float* __restrict__ ws,
                                                    float* __restrict__ out) {
    __shared__ float red[16];
    int t = threadIdx.x, wv = t >> 6, lane = t & 63;
    float m = -3.0e38f;
    for (int v = t; v < V; v += 1024) m = fmaxf(m, out[v]);
    m = wave_reduce_max(m);
    if (lane == 0) red[wv] = m;
    __syncthreads();
    if (t == 0) { float mm = red[0]; for (int i = 1; i < 16; ++i) mm = fmaxf(mm, red[i]); red[0] = mm; }
    __syncthreads();
    m = red[0];
    float s = 0.f;
    for (int v = t; v < V; v += 1024) s += expf(out[v] - m);
    s = wave_reduce_sum(s);
    __syncthreads();
    if (lane == 0) red[wv] = s;
    __syncthreads();
    if (t == 0) { float s2 = 0.f; for (int i = 0; i < 16; ++i) s2 += red[i]; red[0] = s2; }
    __syncthreads();
    float lse = m + logf(red[0]);
    for (int v = t; v < V; v += 1024) out[v] = out[v] - lse;
    if (t < H) out[V + t] = ws[WS_Y + H + t];   // context output
}

extern "C" void kernel_launch(void* const* d_in, const int* in_sizes, int n_in,
                              void* d_out, int out_size, void* d_ws, size_t ws_size,
                              hipStream_t stream) {
    const int*   ids          = (const int*)  d_in[0];
    const float* last_context = (const float*)d_in[1];
    const float* last_hidden  = (const float*)d_in[2];
    const float* enc          = (const float*)d_in[3];
    const float* emb          = (const float*)d_in[4];
    const float* attn_W       = (const float*)d_in[5];
    // d_in[6] = attn_b: contributes a softmax-invariant constant -> exactly droppable
    const float* Wih          = (const float*)d_in[7];
    const float* Whh          = (const float*)d_in[8];
    const float* bih          = (const float*)d_in[9];
    const float* bhh          = (const float*)d_in[10];
    const float* outW         = (const float*)d_in[11];
    const float* outb         = (const float*)d_in[12];
    float* out = (float*)d_out;
    float* ws  = (float*)d_ws;

    hipLaunchKernelGGL(k0_prep,    dim3(8),            dim3(256),  0, stream, ids, last_context, emb, ws);
    hipLaunchKernelGGL(k1_gru_mv,  dim3(H3 / 4),       dim3(256),  0, stream, Wih, Whh, bih, bhh, last_hidden, ws);
    hipLaunchKernelGGL(k2_gates,   dim3(H / 256),      dim3(256),  0, stream, last_hidden, ws, out);
    hipLaunchKernelGGL(k3_u,       dim3(64),           dim3(256),  0, stream, attn_W, ws);
    hipLaunchKernelGGL(k4_energy,  dim3(S / 4),        dim3(256),  0, stream, enc, ws);
    hipLaunchKernelGGL(k5_softmax, dim3(1),            dim3(1024), 0, stream, ws, out);
    hipLaunchKernelGGL(k6_ctx,     dim3(64),           dim3(256),  0, stream, enc, ws);
    hipLaunchKernelGGL(k7_logits,  dim3((V + 3) / 4),  dim3(256),  0, stream, outW, outb, ws, out);
    hipLaunchKernelGGL(k8_finalize,dim3(1),            dim3(1024), 0, stream, ws, out);
}